// Round 14
// baseline (178.330 us; speedup 1.0000x reference)
//
#include <hip/hip_runtime.h>

#define BB 4
#define QQ 256
#define VV 2048
#define HH 512
#define UU 128

// tanh arg scale folded into projections: C2E = 2*log2(e); exp(x)=exp2(x*LOG2E)
#define C2E   2.8853900817779268f
#define LOG2E 1.4426950408889634f

typedef __attribute__((ext_vector_type(8))) short bf16x8;
typedef __attribute__((ext_vector_type(4))) float f32x4;

__device__ __forceinline__ void fma4(float4& a, float s, const float4& w) {
    a.x = fmaf(s, w.x, a.x);
    a.y = fmaf(s, w.y, a.y);
    a.z = fmaf(s, w.z, a.z);
    a.w = fmaf(s, w.w, a.w);
}
__device__ __forceinline__ float2 rcp2(float2 x) {
    return make_float2(__builtin_amdgcn_rcpf(x.x), __builtin_amdgcn_rcpf(x.y));
}
__device__ __forceinline__ float2 mul2(float2 a, float2 b) { return make_float2(a.x*b.x, a.y*b.y); }
__device__ __forceinline__ float2 muls(float2 a, float s)  { return make_float2(a.x*s, a.y*s); }
__device__ __forceinline__ float2 fma2(float2 a, float2 b, float2 c) {
    return make_float2(fmaf(a.x, b.x, c.x), fmaf(a.y, b.y, c.y));
}
__device__ __forceinline__ float2 fmas(float2 a, float s, float2 c) {
    return make_float2(fmaf(a.x, s, c.x), fmaf(a.y, s, c.y));
}
// bf16 round-to-nearest-even split helpers
__device__ __forceinline__ unsigned short f2bf(float x) {
    unsigned int u = __float_as_uint(x);
    u += 0x7fff + ((u >> 16) & 1);
    return (unsigned short)(u >> 16);
}
__device__ __forceinline__ float bf2f(unsigned short h) {
    return __uint_as_float(((unsigned int)h) << 16);
}

// ---------------------------------------------------------------------------
// proj (blocks 0..575): GEMM -> exponentiated interleaved E at (g*ROWS+r)*4+j
//   16 rows x 128 u, 128 threads, 4 rows x 4 u per thread.
// prep (blocks 576..1599): values -> vThi/vTlo [b][h][v] bf16 hi/lo split,
//   64x64 tiles via LDS transpose (phase-B MFMA B-operand layout: one 16B
//   load per lane fragment).
// Block 0 zeroes denom[1024].
// ---------------------------------------------------------------------------
__global__ __launch_bounds__(128) void proj_kernel(const float* __restrict__ queries,
                                                   const float* __restrict__ values,
                                                   const float* __restrict__ w1,
                                                   const float* __restrict__ w2,
                                                   float* __restrict__ pqI,
                                                   float* __restrict__ pvI,
                                                   unsigned short* __restrict__ vThi,
                                                   unsigned short* __restrict__ vTlo,
                                                   float* __restrict__ denom) {
    __shared__ float smem[4736];                 // As[32][20]|Ws[32*128] ; prep S[64][68]
    const int bid = blockIdx.x;
    const int tid = threadIdx.x;

    if (bid >= 576) {                            // ---- prep: transpose+bf16-split ----
        const int t = bid - 576;                 // 0..1023
        const int b = t >> 8, tt = t & 255;
        const int v0 = (tt >> 3) * 64, h0 = (tt & 7) * 64;
        float (*S)[68] = (float(*)[68])smem;
#pragma unroll
        for (int j = 0; j < 8; j++) {
            const int f = tid + j * 128;
            const int vr = f >> 4, c4 = (f & 15) * 4;
            const float4 a = *(const float4*)&values[((size_t)(b * VV + v0 + vr)) * HH + h0 + c4];
            S[vr][c4 + 0] = a.x; S[vr][c4 + 1] = a.y;
            S[vr][c4 + 2] = a.z; S[vr][c4 + 3] = a.w;
        }
        __syncthreads();
        const int hr = tid >> 1, half = (tid & 1) * 32;
        const size_t rowo = ((size_t)(b * HH + h0 + hr)) * VV + v0 + half;
#pragma unroll
        for (int c = 0; c < 32; c += 2) {
            const float x0 = S[half + c][hr], x1 = S[half + c + 1][hr];
            const unsigned short h0b = f2bf(x0), h1b = f2bf(x1);
            const unsigned short l0b = f2bf(x0 - bf2f(h0b)), l1b = f2bf(x1 - bf2f(h1b));
            *(ushort2*)&vThi[rowo + c] = make_ushort2(h0b, h1b);
            *(ushort2*)&vTlo[rowo + c] = make_ushort2(l0b, l1b);
        }
        return;
    }

    float (*As)[20] = (float(*)[20])smem;        // [k][row]
    float* Ws = smem + 32 * 20;                  // [k][u]
    float (*Ls)[20] = (float(*)[20])smem;        // [u][row], epilogue

    if (bid == 0) {
        *(float4*)&denom[tid * 8]     = make_float4(0.f, 0.f, 0.f, 0.f);
        *(float4*)&denom[tid * 8 + 4] = make_float4(0.f, 0.f, 0.f, 0.f);
    }

    const bool isv = (bid < 512);
    const float* A; const float* W; int b, r0, ROWS; float* Ob;
    if (isv) {                             // values: 8192 rows
        b = bid >> 7; r0 = (bid & 127) * 16;
        A = values + ((size_t)(b * VV + r0)) * HH;  W = w2;
        Ob = pvI + (size_t)b * UU * VV;  ROWS = VV;
    } else {                               // queries: 1024 rows
        const int q = bid - 512;
        b = q >> 4; r0 = (q & 15) * 16;
        A = queries + ((size_t)(b * QQ + r0)) * HH; W = w1;
        Ob = pqI + (size_t)b * UU * QQ;  ROWS = QQ;
    }

    const int tx = tid & 31;         // u-group
    const int ty = tid >> 5;         // row-quad
    float4 acc[4];
#pragma unroll
    for (int j = 0; j < 4; j++) acc[j] = make_float4(0.f, 0.f, 0.f, 0.f);

    for (int k0 = 0; k0 < HH; k0 += 32) {
        {   // A tile: 16 rows x 32 k, transposed
            const int r = tid >> 3, kk4 = (tid & 7) * 4;
            const float4 a = *(const float4*)&A[(size_t)r * HH + k0 + kk4];
            As[kk4 + 0][r] = a.x; As[kk4 + 1][r] = a.y;
            As[kk4 + 2][r] = a.z; As[kk4 + 3][r] = a.w;
        }
#pragma unroll
        for (int t = 0; t < 8; t++) {  // W tile: 32 k x 128 u
            const int f = tid + t * 128;
            const int kk = f >> 5, u4 = (f & 31) * 4;
            *(float4*)&Ws[kk * 128 + u4] = *(const float4*)&W[(size_t)(k0 + kk) * UU + u4];
        }
        __syncthreads();
#pragma unroll
        for (int kk = 0; kk < 32; kk++) {
            const float4 a = *(const float4*)&As[kk][ty * 4];
            const float4 w = *(const float4*)&Ws[kk * 128 + tx * 4];
            fma4(acc[0], a.x, w);
            fma4(acc[1], a.y, w);
            fma4(acc[2], a.z, w);
            fma4(acc[3], a.w, w);
        }
        __syncthreads();
    }
#pragma unroll
    for (int j = 0; j < 4; j++) {
        const float aa[4] = {acc[j].x, acc[j].y, acc[j].z, acc[j].w};
#pragma unroll
        for (int i = 0; i < 4; i++)
            Ls[tx * 4 + i][ty * 4 + j] = __builtin_amdgcn_exp2f(aa[i] * C2E);
    }
    __syncthreads();
#pragma unroll
    for (int t = 0; t < 4; t++) {    // 512 float4 chunks
        const int idx = tid + t * 128;
        const int g = idx >> 4, r = idx & 15;
        float4 o;
        o.x = Ls[4 * g + 0][r]; o.y = Ls[4 * g + 1][r];
        o.z = Ls[4 * g + 2][r]; o.w = Ls[4 * g + 3][r];
        *(float4*)&Ob[((size_t)g * ROWS + r0 + r) * 4] = o;
    }
}

// ---------------------------------------------------------------------------
// Fused scores+softmax-numerator+partial-out. grid = 4b*16qb*16vs = 1024,
// 256 threads (4 waves), bounds(256,4).
// Phase A: exp-product grouped-rcp (unchanged R13); epilogue writes att as
//   SPLIT-bf16 (hi+lo) directly into MFMA-A-layout LDS [q=m][k=v], rows
//   padded to 136 shorts (2-way LDS conflicts only).
// Phase B (R14): MFMA 16x16x32 bf16 — (16q x 128v)·(128v x 128h per wave).
//   3-product split (ahi*vhi + ahi*vlo + alo*vhi) keeps error ~2^-17 vs the
//   2.87e-3 threshold. 96 MFMA/wave replaces ~24 us/SIMD of VALU+LDS issue.
// ---------------------------------------------------------------------------
__global__ __launch_bounds__(256, 4) void fused_kernel(const float* __restrict__ pqI,
                                                       const float* __restrict__ pvI,
                                                       const float* __restrict__ vvec,
                                                       const unsigned short* __restrict__ vThi,
                                                       const unsigned short* __restrict__ vTlo,
                                                       float* __restrict__ slab,
                                                       float* __restrict__ denom) {
    __shared__ float cbuf[128][16];                    // 8 KB phase-A u-half combine
    __shared__ __align__(16) unsigned short attHi[16][136];  // A-layout [m=q][k=v]
    __shared__ __align__(16) unsigned short attLo[16][136];
    __shared__ float wred[2][16];
    const int tid = threadIdx.x;
    const int bid = blockIdx.x;
    const int vs = bid & 15, qb = (bid >> 4) & 15, b = bid >> 8;
    const int qbase = qb * 16, vbase = vs * 128;

    // ---- Phase A ----
    const int vloc = tid & 127, uh = tid >> 7;      // uh wave-uniform
    const int v = vbase + vloc;

    float vsum = 0.0f;
#pragma unroll
    for (int u4 = 0; u4 < UU; u4 += 4) {
        const float4 t = *(const float4*)&vvec[u4];
        vsum += t.x + t.y + t.z + t.w;
    }

    const float* pv4 = pvI + (size_t)b * UU * VV + (size_t)v * 4;      // Ev
    const float* pq4 = pqI + (size_t)b * UU * QQ + (size_t)qbase * 4;  // Eq blocks

    float2 acc[8];
#pragma unroll
    for (int p = 0; p < 8; p++) acc[p] = make_float2(0.f, 0.f);

    const int G0 = uh * 16;
    float4 ev = *(const float4*)&pv4[(size_t)G0 * VV * 4];   // prefetch g=0

    for (int g = 0; g < 16; g++) {
        const int G = G0 + g;
        const float* eqp = &pq4[(size_t)G * QQ * 4];  // 16q x 4u, contiguous, uniform
        float4 evn;
        if (g < 15) evn = *(const float4*)&pv4[(size_t)(G + 1) * VV * 4];
        const float4 wq = *(const float4*)&vvec[G * 4];
        const float w0 = 2.f * wq.x, w1 = 2.f * wq.y;
        const float w2 = 2.f * wq.z, w3 = 2.f * wq.w;
#pragma unroll
        for (int p = 0; p < 8; p++) {
            const float4 e0 = *(const float4*)&eqp[(2 * p) * 4];
            const float4 e1 = *(const float4*)&eqp[(2 * p + 1) * 4];
            const float2 a1 = make_float2(fmaf(e0.x, ev.x, 1.f), fmaf(e1.x, ev.x, 1.f));
            const float2 b1 = make_float2(fmaf(e0.y, ev.y, 1.f), fmaf(e1.y, ev.y, 1.f));
            const float2 c1 = make_float2(fmaf(e0.z, ev.z, 1.f), fmaf(e1.z, ev.z, 1.f));
            const float2 d1 = make_float2(fmaf(e0.w, ev.w, 1.f), fmaf(e1.w, ev.w, 1.f));
            const float2 pab = mul2(a1, b1), pcd = mul2(c1, d1);
            const float2 nab = fmas(a1, w1, muls(b1, w0));
            const float2 ncd = fmas(c1, w3, muls(d1, w2));
            const float2 num = fma2(nab, pcd, mul2(ncd, pab));
            const float2 den = mul2(pab, pcd);
            acc[p] = fma2(num, rcp2(den), acc[p]);
        }
        ev = evn;
    }

    // u-half combine: uh=1 dumps raw partials; uh=0 finishes + writes bf16 att
    if (uh == 1) {
#pragma unroll
        for (int p = 0; p < 8; p++)
            *(float2*)&cbuf[vloc][2 * p] = acc[p];
    }
    __syncthreads();
    if (uh == 0) {
#pragma unroll
        for (int p = 0; p < 8; p++) {
            const float2 hi = *(const float2*)&cbuf[vloc][2 * p];
            float2 e;
            e.x = __builtin_amdgcn_exp2f((vsum - (acc[p].x + hi.x)) * LOG2E);
            e.y = __builtin_amdgcn_exp2f((vsum - (acc[p].y + hi.y)) * LOG2E);
            const unsigned short hx = f2bf(e.x), hy = f2bf(e.y);
            attHi[2 * p + 0][vloc] = hx;
            attHi[2 * p + 1][vloc] = hy;
            attLo[2 * p + 0][vloc] = f2bf(e.x - bf2f(hx));
            attLo[2 * p + 1][vloc] = f2bf(e.y - bf2f(hy));
            acc[p] = e;
        }
#pragma unroll
        for (int off = 1; off < 64; off <<= 1) {
#pragma unroll
            for (int p = 0; p < 8; p++) {
                acc[p].x += __shfl_xor(acc[p].x, off, 64);
                acc[p].y += __shfl_xor(acc[p].y, off, 64);
            }
        }
        if ((tid & 63) == 0) {
            const int w = tid >> 6;   // 0..1
#pragma unroll
            for (int p = 0; p < 8; p++) {
                wred[w][2 * p + 0] = acc[p].x;
                wred[w][2 * p + 1] = acc[p].y;
            }
        }
    }
    __syncthreads();
    if (tid < 16)
        atomicAdd(&denom[b * QQ + qbase + tid], wred[0][tid] + wred[1][tid]);

    // ---- Phase B: MFMA. wave wv handles h in [wv*128, wv*128+128) ----
    const int lane = tid & 63, wv = tid >> 6;
    const int m = lane & 15, quad = lane >> 4;

    bf16x8 ahi[4], alo[4];
#pragma unroll
    for (int s = 0; s < 4; s++) {
        const int k0 = s * 32 + quad * 8;
        ahi[s] = *(const bf16x8*)(const void*)&attHi[m][k0];
        alo[s] = *(const bf16x8*)(const void*)&attLo[m][k0];
    }

    const unsigned short* vhb = vThi + ((size_t)b * HH + wv * 128) * VV + vbase;
    const unsigned short* vlb = vTlo + ((size_t)b * HH + wv * 128) * VV + vbase;
    float* sp = slab + (size_t)vs * (BB * QQ * HH) + ((size_t)(b * QQ + qbase)) * HH;

#pragma unroll
    for (int t8 = 0; t8 < 8; t8++) {
        const int hrel = t8 * 16 + m;               // h within wave's 128
        const unsigned short* ph = vhb + (size_t)hrel * VV;
        const unsigned short* pl = vlb + (size_t)hrel * VV;
        f32x4 c = {0.f, 0.f, 0.f, 0.f};
#pragma unroll
        for (int s = 0; s < 4; s++) {
            const int kb = s * 32 + quad * 8;
            const bf16x8 bh = *(const bf16x8*)(const void*)&ph[kb];
            const bf16x8 bl = *(const bf16x8*)(const void*)&pl[kb];
            c = __builtin_amdgcn_mfma_f32_16x16x32_bf16(alo[s], bh, c, 0, 0, 0);
            c = __builtin_amdgcn_mfma_f32_16x16x32_bf16(ahi[s], bl, c, 0, 0, 0);
            c = __builtin_amdgcn_mfma_f32_16x16x32_bf16(ahi[s], bh, c, 0, 0, 0);
        }
        const int hh = wv * 128 + hrel;
#pragma unroll
        for (int r = 0; r < 4; r++) {
            const int q = quad * 4 + r;             // C row = q
            sp[(size_t)q * HH + hh] = c[r];
        }
    }
}

// ---------------------------------------------------------------------------
// out = (sum of 16 slabs) * rcp(denom[row]). 131072 float4s, grid 512.
// ---------------------------------------------------------------------------
__global__ __launch_bounds__(256) void reduce_kernel(const float* __restrict__ slab,
                                                     const float* __restrict__ denom,
                                                     float* __restrict__ out) {
    const int i = blockIdx.x * 256 + threadIdx.x;    // float4 index
    const float r = __builtin_amdgcn_rcpf(denom[i >> 7]);
    const float4* s4 = (const float4*)slab;
    float4 s = s4[i];
#pragma unroll
    for (int k = 1; k < 16; k++) {
        const float4 p = s4[(size_t)k * (BB * QQ * HH / 4) + i];
        s.x += p.x; s.y += p.y; s.z += p.z; s.w += p.w;
    }
    s.x *= r; s.y *= r; s.z *= r; s.w *= r;
    ((float4*)out)[i] = s;
}

// ---------------------------------------------------------------------------
extern "C" void kernel_launch(void* const* d_in, const int* in_sizes, int n_in,
                              void* d_out, int out_size, void* d_ws, size_t ws_size,
                              hipStream_t stream) {
    const float* queries = (const float*)d_in[0];  // [B,Q,H]
    const float* values  = (const float*)d_in[1];  // [B,V,H]
    const float* w1      = (const float*)d_in[2];  // [H,U]
    const float* w2      = (const float*)d_in[3];  // [H,U]
    const float* vvec    = (const float*)d_in[4];  // [U]
    float* out = (float*)d_out;

    // ws: pqI[131072 f] | pvI[1048576 f] | denom[1024 f] | slab[16*524288 f] |
    //     vThi[4194304 us] | vTlo[4194304 us]   (~54 MB)
    float* ws    = (float*)d_ws;
    float* pqI   = ws;
    float* pvI   = pqI + BB * UU * QQ;
    float* denom = pvI + (size_t)BB * UU * VV;
    float* slab  = denom + BB * QQ;
    unsigned short* vThi = (unsigned short*)(slab + (size_t)16 * BB * QQ * HH);
    unsigned short* vTlo = vThi + (size_t)BB * HH * VV;

    proj_kernel<<<576 + 1024, 128, 0, stream>>>(queries, values, w1, w2, pqI, pvI,
                                                vThi, vTlo, denom);
    fused_kernel<<<BB * (QQ / 16) * (VV / 128), 256, 0, stream>>>(pqI, pvI, vvec,
                                                                  vThi, vTlo, slab, denom);
    reduce_kernel<<<(BB * QQ * HH) / 4 / 256, 256, 0, stream>>>(slab, denom, out);
}